// Round 7
// baseline (10024.509 us; speedup 1.0000x reference)
//
#include <hip/hip_runtime.h>
#include <stdint.h>
#include <math.h>

#define NB 512
#define NS 200
#define NH 128
#define NH3 384
#define NT 832     // threads/block = 13 waves
#define NWAVE 13

// ---------------- XLA-exact scalar helpers (GRU gate path only) ----------------
__device__ __forceinline__ float xla_tanhf(float x) {
  float cx = fminf(fmaxf(x, -9.0f), 9.0f);
  float x2 = __fmul_rn(cx, cx);
  float p = -2.76076847742355e-16f;
  p = __fadd_rn(__fmul_rn(x2, p), 2.00018790482477e-13f);
  p = __fadd_rn(__fmul_rn(x2, p), -8.60467152213735e-11f);
  p = __fadd_rn(__fmul_rn(x2, p), 5.12229709037114e-08f);
  p = __fadd_rn(__fmul_rn(x2, p), 1.48572235717979e-05f);
  p = __fadd_rn(__fmul_rn(x2, p), 6.37261928875436e-04f);
  p = __fadd_rn(__fmul_rn(x2, p), 4.89352455891786e-03f);
  p = __fmul_rn(cx, p);
  float q = 1.19825839466702e-06f;
  q = __fadd_rn(__fmul_rn(x2, q), 1.18534705686654e-04f);
  q = __fadd_rn(__fmul_rn(x2, q), 2.26843463243900e-03f);
  q = __fadd_rn(__fmul_rn(x2, q), 4.89352518554385e-03f);
  float r = __fdiv_rn(p, q);
  return (fabsf(x) < 0.0004f) ? x : r;
}

__device__ __forceinline__ float xla_sigmoidf(float x) {
  return __fadd_rn(0.5f, __fmul_rn(0.5f, xla_tanhf(__fmul_rn(0.5f, x))));
}

// fast tanh for logit paths (S4/S5): fma-Horner + rcp/Newton div.
// |diff vs xla_tanhf| <= ~3 ulp; logits are non-compounding, indices safe.
__device__ __forceinline__ float fast_tanhf(float x) {
  float cx = fminf(fmaxf(x, -9.0f), 9.0f);
  float x2 = __fmul_rn(cx, cx);
  float p = fmaf(x2, -2.76076847742355e-16f, 2.00018790482477e-13f);
  p = fmaf(x2, p, -8.60467152213735e-11f);
  p = fmaf(x2, p, 5.12229709037114e-08f);
  p = fmaf(x2, p, 1.48572235717979e-05f);
  p = fmaf(x2, p, 6.37261928875436e-04f);
  p = fmaf(x2, p, 4.89352455891786e-03f);
  p = __fmul_rn(cx, p);
  float q = fmaf(x2, 1.19825839466702e-06f, 1.18534705686654e-04f);
  q = fmaf(x2, q, 2.26843463243900e-03f);
  q = fmaf(x2, q, 4.89352518554385e-03f);
  float r = __builtin_amdgcn_rcpf(q);
  float e = fmaf(-q, r, 1.0f);
  r = fmaf(r, e, r);                 // 1 Newton step -> ~0.5 ulp reciprocal
  return __fmul_rn(p, r);
}

__device__ __forceinline__ uint32_t rotl32(uint32_t v, int r) {
  return (v << r) | (v >> (32 - r));
}
__device__ __forceinline__ void threefry2x32(uint32_t k0, uint32_t k1,
                                             uint32_t x0, uint32_t x1,
                                             uint32_t& o0, uint32_t& o1) {
  uint32_t k2 = k0 ^ k1 ^ 0x1BD11BDAu;
  x0 += k0; x1 += k1;
  #define TFR(r) { x0 += x1; x1 = rotl32(x1, r); x1 ^= x0; }
  TFR(13) TFR(15) TFR(26) TFR(6)
  x0 += k1; x1 += k2 + 1u;
  TFR(17) TFR(29) TFR(16) TFR(24)
  x0 += k2; x1 += k0 + 2u;
  TFR(13) TFR(15) TFR(26) TFR(6)
  x0 += k0; x1 += k1 + 3u;
  TFR(17) TFR(29) TFR(16) TFR(24)
  x0 += k1; x1 += k2 + 4u;
  TFR(13) TFR(15) TFR(26) TFR(6)
  x0 += k2; x1 += k0 + 5u;
  #undef TFR
  o0 = x0; o1 = x1;
}

__device__ __forceinline__ float bits_to_gumbel(uint32_t bits) {
  const float kTiny = 1.1754943508222875e-38f;
  float f = __fsub_rn(__uint_as_float((bits >> 9) | 0x3F800000u), 1.0f);
  float u = __fadd_rn(__fmul_rn(f, __fsub_rn(1.0f, kTiny)), kTiny);
  u = fmaxf(kTiny, u);
  return -logf(-logf(u));
}

// ---------------- persistent kernel: 1 row/block, 832 threads ----------------
// S4/S5 task map: t<800 -> s = t>>2 (0..199), q = t&3 handles h = q+4j, j<32
__global__ __launch_bounds__(NT, 6) void k_decode(
    const float* __restrict__ stat, const float* __restrict__ dyn,
    const float* __restrict__ sW,   const float* __restrict__ sb,
    const float* __restrict__ dW,   const float* __restrict__ db,
    const float* __restrict__ x0,   const float* __restrict__ h0,
    const float* __restrict__ Wemb, const float* __restrict__ bemb,
    const float* __restrict__ Wih,  const float* __restrict__ Whh,
    const float* __restrict__ bih,  const float* __restrict__ bhh,
    const float* __restrict__ Wa,   const float* __restrict__ va,
    const float* __restrict__ Wd,   const float* __restrict__ vd,
    float* __restrict__ out) {

  __shared__ __align__(16) float st0L[NS], st1L[NS], dy0L[NS], dy1L[NS];
  __shared__ float4 AF4[NH];               // {As0,As1,Ad0,Ad1}
  __shared__ float2 AF2[NH];               // {Ac, va}
  __shared__ float4 DF4[NH];               // {Ds0,Ds1,Dc,vd}
  __shared__ float4 CW4[NH];               // {Cw0,Cw1,Cwb,0}
  __shared__ float WembL[2*NH], bembL[NH];
  __shared__ float bihL[NH3], bhhL[NH3];
  __shared__ __align__(16) float embL[NH], hL[NH];
  __shared__ float giL[NH3], ghL[NH3];
  __shared__ float HtL[NH];                // Hterm, overwritten by Cterm
  __shared__ float ex2L[NS];
  __shared__ uint32_t keysL[2*NS];
  __shared__ float xpL[2];
  __shared__ float part[NWAVE][8];
  __shared__ int   partI[NWAVE];

  const int t = threadIdx.x;
  const int b = blockIdx.x;
  const int w = t >> 6;                    // wave 0..12
  const int s = t >> 2;                    // candidate node
  const int q = t & 3;                     // h-quarter
  const bool activeS = (t < 800);          // 800 = 200 s * 4 quarters exactly

  // ---- one-time setup ----
  if (t < NS) {
    st0L[t] = stat[(size_t)b*2*NS + t];
    st1L[t] = stat[(size_t)b*2*NS + NS + t];
    dy0L[t] = dyn[(size_t)b*2*NS + t];
    dy1L[t] = dyn[(size_t)b*2*NS + NS + t];
    uint32_t q0, q1;
    threefry2x32(0u, 42u, 0u, (uint32_t)t, q0, q1);
    keysL[2*t] = q0; keysL[2*t + 1] = q1;
  }
  if (t < NH) {
    int h = t;
    const float* war = Wa + (size_t)h * NH3;
    float as0 = 0.f, as1 = 0.f, ad0 = 0.f, ad1 = 0.f, ac = 0.f;
    for (int k = 0; k < NH; ++k) {
      as0 = fmaf(war[k],     sW[k*2+0], as0);
      as1 = fmaf(war[k],     sW[k*2+1], as1);
      ad0 = fmaf(war[NH+k],  dW[k*2+0], ad0);
      ad1 = fmaf(war[NH+k],  dW[k*2+1], ad1);
      ac  = fmaf(war[k],     sb[k],     ac);
    }
    for (int k = 0; k < NH; ++k) ac = fmaf(war[NH+k], db[k], ac);
    AF4[h] = make_float4(as0, as1, ad0, ad1);
    AF2[h] = make_float2(ac, va[h]);

    const float* wdr = Wd + (size_t)h * 256;
    float ds0 = 0.f, ds1 = 0.f, dc = 0.f, c0 = 0.f, c1 = 0.f, cb = 0.f;
    for (int k = 0; k < NH; ++k) {
      ds0 = fmaf(wdr[k],    sW[k*2+0], ds0);
      ds1 = fmaf(wdr[k],    sW[k*2+1], ds1);
      dc  = fmaf(wdr[k],    sb[k],     dc);
      c0  = fmaf(wdr[NH+k], sW[k*2+0], c0);
      c1  = fmaf(wdr[NH+k], sW[k*2+1], c1);
      cb  = fmaf(wdr[NH+k], sb[k],     cb);
    }
    DF4[h] = make_float4(ds0, ds1, dc, vd[h]);
    CW4[h] = make_float4(c0, c1, cb, 0.f);

    bembL[h] = bemb[h];
    WembL[2*h]   = Wemb[2*h];
    WembL[2*h+1] = Wemb[2*h+1];
    hL[h] = h0[h];
  }
  for (int i = t; i < NH3; i += NT) { bihL[i] = bih[i]; bhhL[i] = bhh[i]; }
  if (t == 0) { xpL[0] = x0[0]; xpL[1] = x0[1]; }
  __syncthreads();

  // per-s inputs hoisted (quad-uniform)
  float s0r = 0.f, s1r = 0.f, d0r = 0.f, d1r = 0.f;
  if (activeS) { s0r = st0L[s]; s1r = st1L[s]; d0r = dy0L[s]; d1r = dy1L[s]; }

  // GRU dot row pointer (fixed per thread; waves 0-5 Wih, 6-11 Whh, 12 idle)
  const float4* wrow = (t < NH3) ? (const float4*)(Wih + (size_t)t * NH)
                     : (t < 2*NH3) ? (const float4*)(Whh + (size_t)(t - NH3) * NH)
                     : (const float4*)Wih;

  // ---- 200 decode steps ----
  for (int step = 0; step < NS; ++step) {
    // S0: emb = x @ Wemb^T + bemb (t<128)
    if (t < NH) {
      float e = fmaf(xpL[1], WembL[t*2+1], __fmul_rn(xpL[0], WembL[t*2+0]));
      embL[t] = __fadd_rn(e, bembL[t]);
    }
    __syncthreads();

    // S1: 768 GRU dots, one per thread (bit-identical per-dot chain)
    if (t < 2*NH3) {
      const float4* op = (t < NH3) ? (const float4*)embL : (const float4*)hL;
      float a0 = 0.f;
      #pragma unroll 8
      for (int k4 = 0; k4 < 32; ++k4) {
        float4 c = wrow[k4], v = op[k4];
        a0 = fmaf(c.x, v.x, a0); a0 = fmaf(c.y, v.y, a0);
        a0 = fmaf(c.z, v.z, a0); a0 = fmaf(c.w, v.w, a0);
      }
      if (t < NH3) giL[t]       = __fadd_rn(a0, bihL[t]);
      else         ghL[t - NH3] = __fadd_rn(a0, bhhL[t - NH3]);
    }
    __syncthreads();

    // S2: gates (torch r,z,n) with EXACT XLA math, h_new in place (t<128)
    if (t < NH) {
      float r = xla_sigmoidf(__fadd_rn(giL[t],      ghL[t]));
      float z = xla_sigmoidf(__fadd_rn(giL[t+NH],   ghL[t+NH]));
      float n = xla_tanhf(__fadd_rn(giL[t+2*NH], __fmul_rn(r, ghL[t+2*NH])));
      float hv = hL[t];
      hL[t] = __fadd_rn(__fmul_rn(__fsub_rn(1.0f, z), n), __fmul_rn(z, hv));
    }
    __syncthreads();

    // S3: Hterm = Wa[:,256:384] @ h_new (exact chain, t<128)
    if (t < NH) {
      const float4* war = (const float4*)(Wa + (size_t)t*NH3 + 2*NH);
      const float4* hn4 = (const float4*)hL;
      float acc = 0.f;
      #pragma unroll 8
      for (int k4 = 0; k4 < 32; ++k4) {
        float4 a = war[k4], hv = hn4[k4];
        acc = fmaf(a.x, hv.x, acc); acc = fmaf(a.y, hv.y, acc);
        acc = fmaf(a.z, hv.z, acc); acc = fmaf(a.w, hv.w, acc);
      }
      HtL[t] = acc;
    }
    __syncthreads();

    // S4: attention scores; quarter-partials, stride-4 h (conflict-free)
    float acc = 0.f;
    if (activeS) {
      #pragma unroll 8
      for (int j = 0; j < 32; ++j) {
        int h = q + 4*j;
        float4 af = AF4[h]; float2 a2 = AF2[h]; float ht = HtL[h];
        float e = fmaf(af.y, s1r, __fmul_rn(af.x, s0r));
        e = fmaf(af.z, d0r, e);
        e = fmaf(af.w, d1r, e);
        e = __fadd_rn(e, a2.x);
        e = __fadd_rn(e, ht);
        acc = fmaf(a2.y, fast_tanhf(e), acc);
      }
    }
    // quad combine -> sc on all 4 quad lanes
    float v = __fadd_rn(acc, __shfl_xor(acc, 1));
    v = __fadd_rn(v, __shfl_xor(v, 2));
    float sc = activeS ? v : -INFINITY;

    // wave max over distinct s (quad-uniform -> xor 4..32)
    {
      float m = sc;
      m = fmaxf(m, __shfl_xor(m, 4));
      m = fmaxf(m, __shfl_xor(m, 8));
      m = fmaxf(m, __shfl_xor(m, 16));
      m = fmaxf(m, __shfl_xor(m, 32));
      if ((t & 63) == 0) part[w][0] = m;
    }
    __syncthreads();
    float mx = part[0][0];
    #pragma unroll
    for (int ww = 1; ww < NWAVE; ++ww) mx = fmaxf(mx, part[ww][0]);

    // exp + sums (each s counted once: quad-uniform values, xor 4..32)
    float exv = activeS ? expf(__fsub_rn(sc, mx)) : 0.f;
    {
      float sm = exv;
      float c0 = __fmul_rn(exv, s0r);
      float c1 = __fmul_rn(exv, s1r);
      #pragma unroll
      for (int mm = 4; mm < 64; mm <<= 1) {
        sm = __fadd_rn(sm, __shfl_xor(sm, mm));
        c0 = __fadd_rn(c0, __shfl_xor(c0, mm));
        c1 = __fadd_rn(c1, __shfl_xor(c1, mm));
      }
      if ((t & 63) == 0) { part[w][1] = sm; part[w][2] = c0; part[w][3] = c1; }
    }
    __syncthreads();

    // Cterm (overwrite HtL), t<128
    if (t < NH) {
      float sume = part[0][1], r0 = part[0][2], r1 = part[0][3];
      #pragma unroll
      for (int ww = 1; ww < NWAVE; ++ww) {
        sume = __fadd_rn(sume, part[ww][1]);
        r0   = __fadd_rn(r0,   part[ww][2]);
        r1   = __fadd_rn(r1,   part[ww][3]);
      }
      r0 = __fdiv_rn(r0, sume); r1 = __fdiv_rn(r1, sume);
      float4 cw = CW4[t];
      HtL[t] = fmaf(r0, cw.x, fmaf(r1, cw.y, cw.z));
    }
    __syncthreads();

    // S5: decoder logits (same task map)
    float accD = 0.f;
    if (activeS) {
      #pragma unroll 8
      for (int j = 0; j < 32; ++j) {
        int h = q + 4*j;
        float4 df = DF4[h]; float ct = HtL[h];
        float d = fmaf(df.y, s1r, __fmul_rn(df.x, s0r));
        d = __fadd_rn(d, df.z);
        d = __fadd_rn(d, ct);
        accD = fmaf(df.w, fast_tanhf(d), accD);
      }
    }
    float v2q = __fadd_rn(accD, __shfl_xor(accD, 1));
    v2q = __fadd_rn(v2q, __shfl_xor(v2q, 2));
    float sc2 = activeS ? v2q : -INFINITY;

    {
      float m = sc2;
      m = fmaxf(m, __shfl_xor(m, 4));
      m = fmaxf(m, __shfl_xor(m, 8));
      m = fmaxf(m, __shfl_xor(m, 16));
      m = fmaxf(m, __shfl_xor(m, 32));
      if ((t & 63) == 0) part[w][4] = m;
    }
    __syncthreads();
    float m2 = part[0][4];
    #pragma unroll
    for (int ww = 1; ww < NWAVE; ++ww) m2 = fmaxf(m2, part[ww][4]);

    // decoder exp/sum + gumbel argmax
    float e2 = activeS ? expf(__fsub_rn(sc2, m2)) : 0.f;
    if (activeS && q == 0) ex2L[s] = e2;
    {
      float sm = e2;
      #pragma unroll
      for (int mm = 4; mm < 64; mm <<= 1) sm = __fadd_rn(sm, __shfl_xor(sm, mm));
      if ((t & 63) == 0) part[w][5] = sm;
    }
    {
      uint32_t k0 = keysL[2*step], k1 = keysL[2*step + 1];
      float gv = -INFINITY;
      int gidx = 1 << 20;
      if (activeS) {
        uint32_t q0, q1;
        threefry2x32(k0, k1, 0u, (uint32_t)(b*NS + s), q0, q1);
        gv = __fadd_rn(bits_to_gumbel(q0 ^ q1), sc2);
        gidx = s;
      }
      #pragma unroll
      for (int mm = 4; mm < 64; mm <<= 1) {
        float ov = __shfl_xor(gv, mm); int oi = __shfl_xor(gidx, mm);
        if (ov > gv || (ov == gv && oi < gidx)) { gv = ov; gidx = oi; }
      }
      if ((t & 63) == 0) { part[w][6] = gv; partI[w] = gidx; }
    }
    __syncthreads();

    if (t == 0) {
      float bv = part[0][6]; int bi = partI[0];
      float sume2 = part[0][5];
      #pragma unroll
      for (int ww = 1; ww < NWAVE; ++ww) {
        float vv = part[ww][6]; int ii = partI[ww];
        if (vv > bv || (vv == bv && ii < bi)) { bv = vv; bi = ii; }
        sume2 = __fadd_rn(sume2, part[ww][5]);
      }
      out[(size_t)b*NS + step] = (float)bi;
      out[(size_t)NB*NS + (size_t)b*NS + step] = __fdiv_rn(ex2L[bi], sume2);
      xpL[0] = st0L[bi]; xpL[1] = st1L[bi];
    }
    __syncthreads();
  }
}

// ---------------- host launch ----------------
extern "C" void kernel_launch(void* const* d_in, const int* in_sizes, int n_in,
                              void* d_out, int out_size, void* d_ws, size_t ws_size,
                              hipStream_t stream) {
  (void)in_sizes; (void)n_in; (void)out_size; (void)d_ws; (void)ws_size;
  const float* stat = (const float*)d_in[0];
  const float* dyn  = (const float*)d_in[1];
  const float* sW   = (const float*)d_in[2];
  const float* sb   = (const float*)d_in[3];
  const float* dW   = (const float*)d_in[4];
  const float* db   = (const float*)d_in[5];
  const float* x0   = (const float*)d_in[6];
  const float* h0   = (const float*)d_in[7];
  const float* Wemb = (const float*)d_in[8];
  const float* bemb = (const float*)d_in[9];
  const float* Wih  = (const float*)d_in[10];
  const float* Whh  = (const float*)d_in[11];
  const float* bih  = (const float*)d_in[12];
  const float* bhh  = (const float*)d_in[13];
  const float* Wa   = (const float*)d_in[14];
  const float* va   = (const float*)d_in[15];
  const float* Wd   = (const float*)d_in[16];
  const float* vd   = (const float*)d_in[17];
  float* out = (float*)d_out;

  k_decode<<<NB, NT, 0, stream>>>(stat, dyn, sW, sb, dW, db, x0, h0,
                                  Wemb, bemb, Wih, Whh, bih, bhh,
                                  Wa, va, Wd, vd, out);
}

// Round 8
// 6942.609 us; speedup vs baseline: 1.4439x; 1.4439x over previous
//
#include <hip/hip_runtime.h>
#include <stdint.h>
#include <math.h>

#define NB 512
#define NS 200
#define NH 128
#define NH3 384
#define NWAVE 8

// ---------------- XLA-exact scalar helpers (GRU gate path only) ----------------
__device__ __forceinline__ float xla_tanhf(float x) {
  float cx = fminf(fmaxf(x, -9.0f), 9.0f);
  float x2 = __fmul_rn(cx, cx);
  float p = -2.76076847742355e-16f;
  p = __fadd_rn(__fmul_rn(x2, p), 2.00018790482477e-13f);
  p = __fadd_rn(__fmul_rn(x2, p), -8.60467152213735e-11f);
  p = __fadd_rn(__fmul_rn(x2, p), 5.12229709037114e-08f);
  p = __fadd_rn(__fmul_rn(x2, p), 1.48572235717979e-05f);
  p = __fadd_rn(__fmul_rn(x2, p), 6.37261928875436e-04f);
  p = __fadd_rn(__fmul_rn(x2, p), 4.89352455891786e-03f);
  p = __fmul_rn(cx, p);
  float q = 1.19825839466702e-06f;
  q = __fadd_rn(__fmul_rn(x2, q), 1.18534705686654e-04f);
  q = __fadd_rn(__fmul_rn(x2, q), 2.26843463243900e-03f);
  q = __fadd_rn(__fmul_rn(x2, q), 4.89352518554385e-03f);
  float r = __fdiv_rn(p, q);
  return (fabsf(x) < 0.0004f) ? x : r;
}

__device__ __forceinline__ float xla_sigmoidf(float x) {
  return __fadd_rn(0.5f, __fmul_rn(0.5f, xla_tanhf(__fmul_rn(0.5f, x))));
}

// fast tanh for logit paths (S4/S5) — validated round 7 (absmax 0.0)
__device__ __forceinline__ float fast_tanhf(float x) {
  float cx = fminf(fmaxf(x, -9.0f), 9.0f);
  float x2 = __fmul_rn(cx, cx);
  float p = fmaf(x2, -2.76076847742355e-16f, 2.00018790482477e-13f);
  p = fmaf(x2, p, -8.60467152213735e-11f);
  p = fmaf(x2, p, 5.12229709037114e-08f);
  p = fmaf(x2, p, 1.48572235717979e-05f);
  p = fmaf(x2, p, 6.37261928875436e-04f);
  p = fmaf(x2, p, 4.89352455891786e-03f);
  p = __fmul_rn(cx, p);
  float q = fmaf(x2, 1.19825839466702e-06f, 1.18534705686654e-04f);
  q = fmaf(x2, q, 2.26843463243900e-03f);
  q = fmaf(x2, q, 4.89352518554385e-03f);
  float r = __builtin_amdgcn_rcpf(q);
  float e = fmaf(-q, r, 1.0f);
  r = fmaf(r, e, r);
  return __fmul_rn(p, r);
}

__device__ __forceinline__ uint32_t rotl32(uint32_t v, int r) {
  return (v << r) | (v >> (32 - r));
}
__device__ __forceinline__ void threefry2x32(uint32_t k0, uint32_t k1,
                                             uint32_t x0, uint32_t x1,
                                             uint32_t& o0, uint32_t& o1) {
  uint32_t k2 = k0 ^ k1 ^ 0x1BD11BDAu;
  x0 += k0; x1 += k1;
  #define TFR(r) { x0 += x1; x1 = rotl32(x1, r); x1 ^= x0; }
  TFR(13) TFR(15) TFR(26) TFR(6)
  x0 += k1; x1 += k2 + 1u;
  TFR(17) TFR(29) TFR(16) TFR(24)
  x0 += k2; x1 += k0 + 2u;
  TFR(13) TFR(15) TFR(26) TFR(6)
  x0 += k0; x1 += k1 + 3u;
  TFR(17) TFR(29) TFR(16) TFR(24)
  x0 += k1; x1 += k2 + 4u;
  TFR(13) TFR(15) TFR(26) TFR(6)
  x0 += k2; x1 += k0 + 5u;
  #undef TFR
  o0 = x0; o1 = x1;
}

__device__ __forceinline__ float bits_to_gumbel(uint32_t bits) {
  const float kTiny = 1.1754943508222875e-38f;
  float f = __fsub_rn(__uint_as_float((bits >> 9) | 0x3F800000u), 1.0f);
  float u = __fadd_rn(__fmul_rn(f, __fsub_rn(1.0f, kTiny)), kTiny);
  u = fmaxf(kTiny, u);
  return -logf(-logf(u));
}

// ---------------- persistent kernel: 1 row/block, 512 threads ----------------
// S4/S5 task map: t<400 -> s = t>>1 (0..199), half = t&1 -> h in [half*64, +64)
// wave 7 idle in S4/S5 (no issue); waves 0-5 full, wave 6 quarter-active.
__global__ __launch_bounds__(512, 4) void k_decode(
    const float* __restrict__ stat, const float* __restrict__ dyn,
    const float* __restrict__ sW,   const float* __restrict__ sb,
    const float* __restrict__ dW,   const float* __restrict__ db,
    const float* __restrict__ x0,   const float* __restrict__ h0,
    const float* __restrict__ Wemb, const float* __restrict__ bemb,
    const float* __restrict__ Wih,  const float* __restrict__ Whh,
    const float* __restrict__ bih,  const float* __restrict__ bhh,
    const float* __restrict__ Wa,   const float* __restrict__ va,
    const float* __restrict__ Wd,   const float* __restrict__ vd,
    float* __restrict__ out) {

  __shared__ __align__(16) float st0L[NS], st1L[NS], dy0L[NS], dy1L[NS];
  __shared__ float4 AF4[NH];               // {As0,As1,Ad0,Ad1}
  __shared__ float2 AF2[NH];               // {Ac, va}
  __shared__ float4 DF4[NH];               // {Ds0,Ds1,Dc,vd}
  __shared__ float4 CW4[NH];               // {Cw0,Cw1,Cwb,0}
  __shared__ float WembL[2*NH], bembL[NH];
  __shared__ float bihL[NH3], bhhL[NH3];
  __shared__ __align__(16) float embL[NH], hL[NH];
  __shared__ float giL[NH3], ghL[NH3];
  __shared__ float HtL[NH];                // Hterm, overwritten by Cterm
  __shared__ float ex2L[NS];
  __shared__ uint32_t keysL[2*NS];
  __shared__ float xpL[2];
  __shared__ float part[NWAVE][8];
  __shared__ int   partI[NWAVE];

  const int t = threadIdx.x;
  const int b = blockIdx.x;
  const int w = t >> 6;                    // wave 0..7
  const int s = t >> 1;                    // candidate node (pairs of lanes)
  const int h0i = (t & 1) * 64;            // h-half base
  const bool activeS = (t < 2*NS);         // 400 active task lanes

  // ---- one-time setup ----
  if (t < NS) {
    st0L[t] = stat[(size_t)b*2*NS + t];
    st1L[t] = stat[(size_t)b*2*NS + NS + t];
    dy0L[t] = dyn[(size_t)b*2*NS + t];
    dy1L[t] = dyn[(size_t)b*2*NS + NS + t];
    uint32_t q0, q1;
    threefry2x32(0u, 42u, 0u, (uint32_t)t, q0, q1);
    keysL[2*t] = q0; keysL[2*t + 1] = q1;
  }
  if (t < NH) {
    int h = t;
    const float* war = Wa + (size_t)h * NH3;
    float as0 = 0.f, as1 = 0.f, ad0 = 0.f, ad1 = 0.f, ac = 0.f;
    for (int k = 0; k < NH; ++k) {
      as0 = fmaf(war[k],     sW[k*2+0], as0);
      as1 = fmaf(war[k],     sW[k*2+1], as1);
      ad0 = fmaf(war[NH+k],  dW[k*2+0], ad0);
      ad1 = fmaf(war[NH+k],  dW[k*2+1], ad1);
      ac  = fmaf(war[k],     sb[k],     ac);
    }
    for (int k = 0; k < NH; ++k) ac = fmaf(war[NH+k], db[k], ac);
    AF4[h] = make_float4(as0, as1, ad0, ad1);
    AF2[h] = make_float2(ac, va[h]);

    const float* wdr = Wd + (size_t)h * 256;
    float ds0 = 0.f, ds1 = 0.f, dc = 0.f, c0 = 0.f, c1 = 0.f, cb = 0.f;
    for (int k = 0; k < NH; ++k) {
      ds0 = fmaf(wdr[k],    sW[k*2+0], ds0);
      ds1 = fmaf(wdr[k],    sW[k*2+1], ds1);
      dc  = fmaf(wdr[k],    sb[k],     dc);
      c0  = fmaf(wdr[NH+k], sW[k*2+0], c0);
      c1  = fmaf(wdr[NH+k], sW[k*2+1], c1);
      cb  = fmaf(wdr[NH+k], sb[k],     cb);
    }
    DF4[h] = make_float4(ds0, ds1, dc, vd[h]);
    CW4[h] = make_float4(c0, c1, cb, 0.f);

    bembL[h] = bemb[h];
    WembL[2*h]   = Wemb[2*h];
    WembL[2*h+1] = Wemb[2*h+1];
    hL[h] = h0[h];
  }
  for (int i = t; i < NH3; i += 512) { bihL[i] = bih[i]; bhhL[i] = bhh[i]; }
  if (t == 0) { xpL[0] = x0[0]; xpL[1] = x0[1]; }
  __syncthreads();

  // per-s inputs hoisted (pair-uniform)
  float s0r = 0.f, s1r = 0.f, d0r = 0.f, d1r = 0.f;
  if (activeS) { s0r = st0L[s]; s1r = st1L[s]; d0r = dy0L[s]; d1r = dy1L[s]; }

  // ---- 200 decode steps ----
  for (int step = 0; step < NS; ++step) {
    // S0: emb = x @ Wemb^T + bemb (t<128)
    if (t < NH) {
      float e = fmaf(xpL[1], WembL[t*2+1], __fmul_rn(xpL[0], WembL[t*2+0]));
      embL[t] = __fadd_rn(e, bembL[t]);
    }
    __syncthreads();

    // S1: 768 GRU dots over 512 threads (per-dot chain identical to r5/r6)
    if (t < 256) {
      const float4* wp0 = (const float4*)(Wih + (size_t)t * NH);
      const float4* wp1 = (const float4*)(Whh + (size_t)(NH + t) * NH);
      const float4* e4 = (const float4*)embL;
      const float4* h4 = (const float4*)hL;
      float a0 = 0.f, a1 = 0.f;
      #pragma unroll 8
      for (int k4 = 0; k4 < 32; ++k4) {
        float4 c0 = wp0[k4], c1 = wp1[k4];
        float4 ev = e4[k4],  hv = h4[k4];
        a0 = fmaf(c0.x, ev.x, a0); a0 = fmaf(c0.y, ev.y, a0);
        a0 = fmaf(c0.z, ev.z, a0); a0 = fmaf(c0.w, ev.w, a0);
        a1 = fmaf(c1.x, hv.x, a1); a1 = fmaf(c1.y, hv.y, a1);
        a1 = fmaf(c1.z, hv.z, a1); a1 = fmaf(c1.w, hv.w, a1);
      }
      giL[t]      = __fadd_rn(a0, bihL[t]);
      ghL[NH + t] = __fadd_rn(a1, bhhL[NH + t]);
    } else {
      const bool isWih = (t < NH3);
      const float4* wp = isWih
          ? (const float4*)(Wih + (size_t)t * NH)
          : (const float4*)(Whh + (size_t)(t - NH3) * NH);
      const float4* op = isWih ? (const float4*)embL : (const float4*)hL;
      float a0 = 0.f;
      #pragma unroll 8
      for (int k4 = 0; k4 < 32; ++k4) {
        float4 c = wp[k4], v = op[k4];
        a0 = fmaf(c.x, v.x, a0); a0 = fmaf(c.y, v.y, a0);
        a0 = fmaf(c.z, v.z, a0); a0 = fmaf(c.w, v.w, a0);
      }
      if (isWih) giL[t]       = __fadd_rn(a0, bihL[t]);
      else       ghL[t - NH3] = __fadd_rn(a0, bhhL[t - NH3]);
    }
    __syncthreads();

    // S2: gates (torch r,z,n) EXACT XLA math, h_new in place (t<128)
    if (t < NH) {
      float r = xla_sigmoidf(__fadd_rn(giL[t],      ghL[t]));
      float z = xla_sigmoidf(__fadd_rn(giL[t+NH],   ghL[t+NH]));
      float n = xla_tanhf(__fadd_rn(giL[t+2*NH], __fmul_rn(r, ghL[t+2*NH])));
      float hv = hL[t];
      hL[t] = __fadd_rn(__fmul_rn(__fsub_rn(1.0f, z), n), __fmul_rn(z, hv));
    }
    __syncthreads();

    // S3: Hterm = Wa[:,256:384] @ h_new (exact chain, t<128)
    if (t < NH) {
      const float4* war = (const float4*)(Wa + (size_t)t*NH3 + 2*NH);
      const float4* hn4 = (const float4*)hL;
      float acc = 0.f;
      #pragma unroll 8
      for (int k4 = 0; k4 < 32; ++k4) {
        float4 a = war[k4], hv = hn4[k4];
        acc = fmaf(a.x, hv.x, acc); acc = fmaf(a.y, hv.y, acc);
        acc = fmaf(a.z, hv.z, acc); acc = fmaf(a.w, hv.w, acc);
      }
      HtL[t] = acc;
    }
    __syncthreads();

    // S4: attention scores; half-partials, pair lanes (t, t^1) share s
    float acc = 0.f;
    if (activeS) {
      #pragma unroll 4
      for (int j = 0; j < 64; ++j) {
        int h = h0i + j;
        float4 af = AF4[h]; float2 a2 = AF2[h]; float ht = HtL[h];
        float e = fmaf(af.y, s1r, __fmul_rn(af.x, s0r));
        e = fmaf(af.z, d0r, e);
        e = fmaf(af.w, d1r, e);
        e = __fadd_rn(e, a2.x);
        e = __fadd_rn(e, ht);
        acc = fmaf(a2.y, fast_tanhf(e), acc);
      }
    }
    // pair combine -> sc on both lanes of the pair
    float sc = activeS ? __fadd_rn(acc, __shfl_xor(acc, 1)) : -INFINITY;

    // wave max over distinct s (pair-uniform -> xor 2..32)
    {
      float m = sc;
      #pragma unroll
      for (int mm = 2; mm < 64; mm <<= 1) m = fmaxf(m, __shfl_xor(m, mm));
      if ((t & 63) == 0) part[w][0] = m;
    }
    __syncthreads();
    float mx = part[0][0];
    #pragma unroll
    for (int ww = 1; ww < NWAVE; ++ww) mx = fmaxf(mx, part[ww][0]);

    // exp + sums (each s counted once via even-parity butterfly)
    float exv = activeS ? expf(__fsub_rn(sc, mx)) : 0.f;
    {
      float sm = exv;
      float c0 = __fmul_rn(exv, s0r);
      float c1 = __fmul_rn(exv, s1r);
      #pragma unroll
      for (int mm = 2; mm < 64; mm <<= 1) {
        sm = __fadd_rn(sm, __shfl_xor(sm, mm));
        c0 = __fadd_rn(c0, __shfl_xor(c0, mm));
        c1 = __fadd_rn(c1, __shfl_xor(c1, mm));
      }
      if ((t & 63) == 0) { part[w][1] = sm; part[w][2] = c0; part[w][3] = c1; }
    }
    __syncthreads();

    // Cterm (overwrite HtL), t<128
    if (t < NH) {
      float sume = part[0][1], r0 = part[0][2], r1 = part[0][3];
      #pragma unroll
      for (int ww = 1; ww < NWAVE; ++ww) {
        sume = __fadd_rn(sume, part[ww][1]);
        r0   = __fadd_rn(r0,   part[ww][2]);
        r1   = __fadd_rn(r1,   part[ww][3]);
      }
      r0 = __fdiv_rn(r0, sume); r1 = __fdiv_rn(r1, sume);
      float4 cw = CW4[t];
      HtL[t] = fmaf(r0, cw.x, fmaf(r1, cw.y, cw.z));
    }
    __syncthreads();

    // S5: decoder logits (same task map)
    float accD = 0.f;
    if (activeS) {
      #pragma unroll 4
      for (int j = 0; j < 64; ++j) {
        int h = h0i + j;
        float4 df = DF4[h]; float ct = HtL[h];
        float d = fmaf(df.y, s1r, __fmul_rn(df.x, s0r));
        d = __fadd_rn(d, df.z);
        d = __fadd_rn(d, ct);
        accD = fmaf(df.w, fast_tanhf(d), accD);
      }
    }
    float sc2 = activeS ? __fadd_rn(accD, __shfl_xor(accD, 1)) : -INFINITY;

    {
      float m = sc2;
      #pragma unroll
      for (int mm = 2; mm < 64; mm <<= 1) m = fmaxf(m, __shfl_xor(m, mm));
      if ((t & 63) == 0) part[w][4] = m;
    }
    __syncthreads();
    float m2 = part[0][4];
    #pragma unroll
    for (int ww = 1; ww < NWAVE; ++ww) m2 = fmaxf(m2, part[ww][4]);

    // decoder exp/sum + gumbel argmax
    float e2 = activeS ? expf(__fsub_rn(sc2, m2)) : 0.f;
    if (activeS && (t & 1) == 0) ex2L[s] = e2;
    {
      float sm = e2;
      #pragma unroll
      for (int mm = 2; mm < 64; mm <<= 1) sm = __fadd_rn(sm, __shfl_xor(sm, mm));
      if ((t & 63) == 0) part[w][5] = sm;
    }
    {
      uint32_t k0 = keysL[2*step], k1 = keysL[2*step + 1];
      float gv = -INFINITY;
      int gidx = 1 << 20;
      if (activeS) {
        uint32_t q0, q1;
        threefry2x32(k0, k1, 0u, (uint32_t)(b*NS + s), q0, q1);
        gv = __fadd_rn(bits_to_gumbel(q0 ^ q1), sc2);
        gidx = s;
      }
      #pragma unroll
      for (int mm = 2; mm < 64; mm <<= 1) {
        float ov = __shfl_xor(gv, mm); int oi = __shfl_xor(gidx, mm);
        if (ov > gv || (ov == gv && oi < gidx)) { gv = ov; gidx = oi; }
      }
      if ((t & 63) == 0) { part[w][6] = gv; partI[w] = gidx; }
    }
    __syncthreads();

    if (t == 0) {
      float bv = part[0][6]; int bi = partI[0];
      float sume2 = part[0][5];
      #pragma unroll
      for (int ww = 1; ww < NWAVE; ++ww) {
        float vv = part[ww][6]; int ii = partI[ww];
        if (vv > bv || (vv == bv && ii < bi)) { bv = vv; bi = ii; }
        sume2 = __fadd_rn(sume2, part[ww][5]);
      }
      out[(size_t)b*NS + step] = (float)bi;
      out[(size_t)NB*NS + (size_t)b*NS + step] = __fdiv_rn(ex2L[bi], sume2);
      xpL[0] = st0L[bi]; xpL[1] = st1L[bi];
    }
    __syncthreads();
  }
}

// ---------------- host launch ----------------
extern "C" void kernel_launch(void* const* d_in, const int* in_sizes, int n_in,
                              void* d_out, int out_size, void* d_ws, size_t ws_size,
                              hipStream_t stream) {
  (void)in_sizes; (void)n_in; (void)out_size; (void)d_ws; (void)ws_size;
  const float* stat = (const float*)d_in[0];
  const float* dyn  = (const float*)d_in[1];
  const float* sW   = (const float*)d_in[2];
  const float* sb   = (const float*)d_in[3];
  const float* dW   = (const float*)d_in[4];
  const float* db   = (const float*)d_in[5];
  const float* x0   = (const float*)d_in[6];
  const float* h0   = (const float*)d_in[7];
  const float* Wemb = (const float*)d_in[8];
  const float* bemb = (const float*)d_in[9];
  const float* Wih  = (const float*)d_in[10];
  const float* Whh  = (const float*)d_in[11];
  const float* bih  = (const float*)d_in[12];
  const float* bhh  = (const float*)d_in[13];
  const float* Wa   = (const float*)d_in[14];
  const float* va   = (const float*)d_in[15];
  const float* Wd   = (const float*)d_in[16];
  const float* vd   = (const float*)d_in[17];
  float* out = (float*)d_out;

  k_decode<<<NB, 512, 0, stream>>>(stat, dyn, sW, sb, dW, db, x0, h0,
                                   Wemb, bemb, Wih, Whh, bih, bhh,
                                   Wa, va, Wd, vd, out);
}

// Round 9
// 6714.625 us; speedup vs baseline: 1.4929x; 1.0340x over previous
//
#include <hip/hip_runtime.h>
#include <stdint.h>
#include <math.h>

#define NB 512
#define NS 200
#define NH 128
#define NH3 384
#define NWAVE 8
#define PF 8                     // float4s of primary weight row pinned in VGPRs

// padded LDS index maps (break half-offset bank aliasing)
#define IDX4(h) ((h) + (((h) >> 6) << 2))    // float4 arrays: +4 per 64
#define IDX1(h) ((h) + (((h) >> 6) << 4))    // float  arrays: +16 per 64

// ---------------- XLA-exact scalar helpers (GRU gate path only) ----------------
__device__ __forceinline__ float xla_tanhf(float x) {
  float cx = fminf(fmaxf(x, -9.0f), 9.0f);
  float x2 = __fmul_rn(cx, cx);
  float p = -2.76076847742355e-16f;
  p = __fadd_rn(__fmul_rn(x2, p), 2.00018790482477e-13f);
  p = __fadd_rn(__fmul_rn(x2, p), -8.60467152213735e-11f);
  p = __fadd_rn(__fmul_rn(x2, p), 5.12229709037114e-08f);
  p = __fadd_rn(__fmul_rn(x2, p), 1.48572235717979e-05f);
  p = __fadd_rn(__fmul_rn(x2, p), 6.37261928875436e-04f);
  p = __fadd_rn(__fmul_rn(x2, p), 4.89352455891786e-03f);
  p = __fmul_rn(cx, p);
  float q = 1.19825839466702e-06f;
  q = __fadd_rn(__fmul_rn(x2, q), 1.18534705686654e-04f);
  q = __fadd_rn(__fmul_rn(x2, q), 2.26843463243900e-03f);
  q = __fadd_rn(__fmul_rn(x2, q), 4.89352518554385e-03f);
  float r = __fdiv_rn(p, q);
  return (fabsf(x) < 0.0004f) ? x : r;
}

__device__ __forceinline__ float xla_sigmoidf(float x) {
  return __fadd_rn(0.5f, __fmul_rn(0.5f, xla_tanhf(__fmul_rn(0.5f, x))));
}

// fast tanh for logit paths (S4/S5) — validated rounds 7/8
__device__ __forceinline__ float fast_tanhf(float x) {
  float cx = fminf(fmaxf(x, -9.0f), 9.0f);
  float x2 = __fmul_rn(cx, cx);
  float p = fmaf(x2, -2.76076847742355e-16f, 2.00018790482477e-13f);
  p = fmaf(x2, p, -8.60467152213735e-11f);
  p = fmaf(x2, p, 5.12229709037114e-08f);
  p = fmaf(x2, p, 1.48572235717979e-05f);
  p = fmaf(x2, p, 6.37261928875436e-04f);
  p = fmaf(x2, p, 4.89352455891786e-03f);
  p = __fmul_rn(cx, p);
  float q = fmaf(x2, 1.19825839466702e-06f, 1.18534705686654e-04f);
  q = fmaf(x2, q, 2.26843463243900e-03f);
  q = fmaf(x2, q, 4.89352518554385e-03f);
  float r = __builtin_amdgcn_rcpf(q);
  float e = fmaf(-q, r, 1.0f);
  r = fmaf(r, e, r);
  return __fmul_rn(p, r);
}

__device__ __forceinline__ uint32_t rotl32(uint32_t v, int r) {
  return (v << r) | (v >> (32 - r));
}
__device__ __forceinline__ void threefry2x32(uint32_t k0, uint32_t k1,
                                             uint32_t x0, uint32_t x1,
                                             uint32_t& o0, uint32_t& o1) {
  uint32_t k2 = k0 ^ k1 ^ 0x1BD11BDAu;
  x0 += k0; x1 += k1;
  #define TFR(r) { x0 += x1; x1 = rotl32(x1, r); x1 ^= x0; }
  TFR(13) TFR(15) TFR(26) TFR(6)
  x0 += k1; x1 += k2 + 1u;
  TFR(17) TFR(29) TFR(16) TFR(24)
  x0 += k2; x1 += k0 + 2u;
  TFR(13) TFR(15) TFR(26) TFR(6)
  x0 += k0; x1 += k1 + 3u;
  TFR(17) TFR(29) TFR(16) TFR(24)
  x0 += k1; x1 += k2 + 4u;
  TFR(13) TFR(15) TFR(26) TFR(6)
  x0 += k2; x1 += k0 + 5u;
  #undef TFR
  o0 = x0; o1 = x1;
}

__device__ __forceinline__ float bits_to_gumbel(uint32_t bits) {
  const float kTiny = 1.1754943508222875e-38f;
  float f = __fsub_rn(__uint_as_float((bits >> 9) | 0x3F800000u), 1.0f);
  float u = __fadd_rn(__fmul_rn(f, __fsub_rn(1.0f, kTiny)), kTiny);
  u = fmaxf(kTiny, u);
  return -logf(-logf(u));
}

// ---------------- persistent kernel: 1 row/block, 512 threads ----------------
// S4/S5 task map: t<400 -> s = t>>1, half = t&1 -> h in [half*64, +64)
__global__ __launch_bounds__(512, 4) void k_decode(
    const float* __restrict__ stat, const float* __restrict__ dyn,
    const float* __restrict__ sW,   const float* __restrict__ sb,
    const float* __restrict__ dW,   const float* __restrict__ db,
    const float* __restrict__ x0,   const float* __restrict__ h0,
    const float* __restrict__ Wemb, const float* __restrict__ bemb,
    const float* __restrict__ Wih,  const float* __restrict__ Whh,
    const float* __restrict__ bih,  const float* __restrict__ bhh,
    const float* __restrict__ Wa,   const float* __restrict__ va,
    const float* __restrict__ Wd,   const float* __restrict__ vd,
    float* __restrict__ out) {

  __shared__ __align__(16) float st0L[NS], st1L[NS], dy0L[NS], dy1L[NS];
  __shared__ float4 AF4p[132];             // {As0,As1,Ad0,Ad1} padded
  __shared__ float4 DF4p[132];             // {Ds0,Ds1,vd,Dc}   padded
  __shared__ float4 CW4[NH];               // {Cw0,Cw1,Cwb,0}
  __shared__ float  vaP[144];              // va padded
  __shared__ float  AcL[NH];               // attention const (folded in S3)
  __shared__ float WembL[2*NH], bembL[NH];
  __shared__ float bihL[NH3], bhhL[NH3];
  __shared__ __align__(16) float embL[NH], hL[NH];
  __shared__ float giL[NH3], ghL[NH3];
  __shared__ float HtLp[144];              // Hterm+Ac, then Cterm+Dc (padded)
  __shared__ float ex2L[NS];
  __shared__ uint32_t keysL[2*NS];
  __shared__ float xpL[2];
  __shared__ float part[NWAVE][8];
  __shared__ int   partI[NWAVE];

  const int t = threadIdx.x;
  const int b = blockIdx.x;
  const int w = t >> 6;                    // wave 0..7
  const int s = t >> 1;                    // candidate node (lane pairs)
  const int h0i = (t & 1) * 64;            // h-half base
  const int b4 = h0i + ((h0i >> 6) << 2);  // padded float4 base (0 or 68)
  const int b1 = h0i + ((h0i >> 6) << 4);  // padded float base  (0 or 80)
  const bool activeS = (t < 2*NS);

  // ---- one-time setup ----
  if (t < NS) {
    st0L[t] = stat[(size_t)b*2*NS + t];
    st1L[t] = stat[(size_t)b*2*NS + NS + t];
    dy0L[t] = dyn[(size_t)b*2*NS + t];
    dy1L[t] = dyn[(size_t)b*2*NS + NS + t];
    uint32_t q0, q1;
    threefry2x32(0u, 42u, 0u, (uint32_t)t, q0, q1);
    keysL[2*t] = q0; keysL[2*t + 1] = q1;
  }
  if (t < NH) {
    int h = t;
    const float* war = Wa + (size_t)h * NH3;
    float as0 = 0.f, as1 = 0.f, ad0 = 0.f, ad1 = 0.f, ac = 0.f;
    for (int k = 0; k < NH; ++k) {
      as0 = fmaf(war[k],     sW[k*2+0], as0);
      as1 = fmaf(war[k],     sW[k*2+1], as1);
      ad0 = fmaf(war[NH+k],  dW[k*2+0], ad0);
      ad1 = fmaf(war[NH+k],  dW[k*2+1], ad1);
      ac  = fmaf(war[k],     sb[k],     ac);
    }
    for (int k = 0; k < NH; ++k) ac = fmaf(war[NH+k], db[k], ac);
    AF4p[IDX4(h)] = make_float4(as0, as1, ad0, ad1);
    vaP[IDX1(h)] = va[h];
    AcL[h] = ac;

    const float* wdr = Wd + (size_t)h * 256;
    float ds0 = 0.f, ds1 = 0.f, dc = 0.f, c0 = 0.f, c1 = 0.f, cb = 0.f;
    for (int k = 0; k < NH; ++k) {
      ds0 = fmaf(wdr[k],    sW[k*2+0], ds0);
      ds1 = fmaf(wdr[k],    sW[k*2+1], ds1);
      dc  = fmaf(wdr[k],    sb[k],     dc);
      c0  = fmaf(wdr[NH+k], sW[k*2+0], c0);
      c1  = fmaf(wdr[NH+k], sW[k*2+1], c1);
      cb  = fmaf(wdr[NH+k], sb[k],     cb);
    }
    DF4p[IDX4(h)] = make_float4(ds0, ds1, vd[h], dc);
    CW4[h] = make_float4(c0, c1, cb, 0.f);

    bembL[h] = bemb[h];
    WembL[2*h]   = Wemb[2*h];
    WembL[2*h+1] = Wemb[2*h+1];
    hL[h] = h0[h];
  }
  for (int i = t; i < NH3; i += 512) { bihL[i] = bih[i]; bhhL[i] = bhh[i]; }
  if (t == 0) { xpL[0] = x0[0]; xpL[1] = x0[1]; }
  __syncthreads();

  // per-s inputs hoisted (pair-uniform)
  float s0r = 0.f, s1r = 0.f, d0r = 0.f, d1r = 0.f;
  if (activeS) { s0r = st0L[s]; s1r = st1L[s]; d0r = dy0L[s]; d1r = dy1L[s]; }

  // pin first PF float4 of the primary weight row in registers (step-invariant)
  float4 wreg[PF];
  {
    const float4* wpA = (t < NH3) ? (const float4*)(Wih + (size_t)t * NH)
                                  : (const float4*)(Whh + (size_t)(t - NH3) * NH);
    #pragma unroll
    for (int i = 0; i < PF; ++i) wreg[i] = wpA[i];
  }

  // ---- 200 decode steps ----
  for (int step = 0; step < NS; ++step) {
    // S0: emb = x @ Wemb^T + bemb (t<128)
    if (t < NH) {
      float e = fmaf(xpL[1], WembL[t*2+1], __fmul_rn(xpL[0], WembL[t*2+0]));
      embL[t] = __fadd_rn(e, bembL[t]);
    }
    __syncthreads();

    // S1: 768 GRU dots (per-dot sequential-k chain bit-identical to r5-r8)
    if (t < 256) {
      const float4* wp0 = (const float4*)(Wih + (size_t)t * NH);
      const float4* wp1 = (const float4*)(Whh + (size_t)(NH + t) * NH);
      const float4* e4 = (const float4*)embL;
      const float4* h4 = (const float4*)hL;
      float a0 = 0.f, a1 = 0.f;
      #pragma unroll
      for (int k4 = 0; k4 < PF; ++k4) {
        float4 c0 = wreg[k4], c1 = wp1[k4];
        float4 ev = e4[k4],   hv = h4[k4];
        a0 = fmaf(c0.x, ev.x, a0); a0 = fmaf(c0.y, ev.y, a0);
        a0 = fmaf(c0.z, ev.z, a0); a0 = fmaf(c0.w, ev.w, a0);
        a1 = fmaf(c1.x, hv.x, a1); a1 = fmaf(c1.y, hv.y, a1);
        a1 = fmaf(c1.z, hv.z, a1); a1 = fmaf(c1.w, hv.w, a1);
      }
      #pragma unroll 8
      for (int k4 = PF; k4 < 32; ++k4) {
        float4 c0 = wp0[k4], c1 = wp1[k4];
        float4 ev = e4[k4],  hv = h4[k4];
        a0 = fmaf(c0.x, ev.x, a0); a0 = fmaf(c0.y, ev.y, a0);
        a0 = fmaf(c0.z, ev.z, a0); a0 = fmaf(c0.w, ev.w, a0);
        a1 = fmaf(c1.x, hv.x, a1); a1 = fmaf(c1.y, hv.y, a1);
        a1 = fmaf(c1.z, hv.z, a1); a1 = fmaf(c1.w, hv.w, a1);
      }
      giL[t]      = __fadd_rn(a0, bihL[t]);
      ghL[NH + t] = __fadd_rn(a1, bhhL[NH + t]);
    } else {
      const bool isWih = (t < NH3);
      const float4* wp = isWih
          ? (const float4*)(Wih + (size_t)t * NH)
          : (const float4*)(Whh + (size_t)(t - NH3) * NH);
      const float4* op = isWih ? (const float4*)embL : (const float4*)hL;
      float a0 = 0.f;
      #pragma unroll
      for (int k4 = 0; k4 < PF; ++k4) {
        float4 c = wreg[k4], v = op[k4];
        a0 = fmaf(c.x, v.x, a0); a0 = fmaf(c.y, v.y, a0);
        a0 = fmaf(c.z, v.z, a0); a0 = fmaf(c.w, v.w, a0);
      }
      #pragma unroll 8
      for (int k4 = PF; k4 < 32; ++k4) {
        float4 c = wp[k4], v = op[k4];
        a0 = fmaf(c.x, v.x, a0); a0 = fmaf(c.y, v.y, a0);
        a0 = fmaf(c.z, v.z, a0); a0 = fmaf(c.w, v.w, a0);
      }
      if (isWih) giL[t]       = __fadd_rn(a0, bihL[t]);
      else       ghL[t - NH3] = __fadd_rn(a0, bhhL[t - NH3]);
    }
    __syncthreads();

    // S2: gates (torch r,z,n) EXACT XLA math, h_new in place (t<128)
    if (t < NH) {
      float r = xla_sigmoidf(__fadd_rn(giL[t],      ghL[t]));
      float z = xla_sigmoidf(__fadd_rn(giL[t+NH],   ghL[t+NH]));
      float n = xla_tanhf(__fadd_rn(giL[t+2*NH], __fmul_rn(r, ghL[t+2*NH])));
      float hv = hL[t];
      hL[t] = __fadd_rn(__fmul_rn(__fsub_rn(1.0f, z), n), __fmul_rn(z, hv));
    }
    __syncthreads();

    // S3: Hterm = Wa[:,256:384] @ h_new, +Ac folded (t<128)
    if (t < NH) {
      const float4* war = (const float4*)(Wa + (size_t)t*NH3 + 2*NH);
      const float4* hn4 = (const float4*)hL;
      float acc = 0.f;
      #pragma unroll 8
      for (int k4 = 0; k4 < 32; ++k4) {
        float4 a = war[k4], hv = hn4[k4];
        acc = fmaf(a.x, hv.x, acc); acc = fmaf(a.y, hv.y, acc);
        acc = fmaf(a.z, hv.z, acc); acc = fmaf(a.w, hv.w, acc);
      }
      HtLp[IDX1(t)] = __fadd_rn(acc, AcL[t]);
    }
    __syncthreads();

    // S4: attention scores; half-partials, padded LDS (conflict-free)
    float acc = 0.f;
    if (activeS) {
      #pragma unroll 4
      for (int j = 0; j < 64; ++j) {
        float4 af = AF4p[b4 + j];
        float vah = vaP[b1 + j];
        float ath = HtLp[b1 + j];
        float e = fmaf(af.y, s1r, __fmul_rn(af.x, s0r));
        e = fmaf(af.z, d0r, e);
        e = fmaf(af.w, d1r, e);
        e = __fadd_rn(e, ath);
        acc = fmaf(vah, fast_tanhf(e), acc);
      }
    }
    float sc = activeS ? __fadd_rn(acc, __shfl_xor(acc, 1)) : 0.f;

    // raw exp (no max-sub; bounded logits, fp32-safe) + sums butterfly
    float exv = activeS ? expf(sc) : 0.f;
    {
      float sm = exv;
      float c0 = __fmul_rn(exv, s0r);
      float c1 = __fmul_rn(exv, s1r);
      #pragma unroll
      for (int mm = 2; mm < 64; mm <<= 1) {
        sm = __fadd_rn(sm, __shfl_xor(sm, mm));
        c0 = __fadd_rn(c0, __shfl_xor(c0, mm));
        c1 = __fadd_rn(c1, __shfl_xor(c1, mm));
      }
      if ((t & 63) == 0) { part[w][0] = sm; part[w][1] = c0; part[w][2] = c1; }
    }
    __syncthreads();

    // Cterm (overwrite HtLp), +Dc folded, t<128
    if (t < NH) {
      float sume = part[0][0], r0 = part[0][1], r1 = part[0][2];
      #pragma unroll
      for (int ww = 1; ww < NWAVE; ++ww) {
        sume = __fadd_rn(sume, part[ww][0]);
        r0   = __fadd_rn(r0,   part[ww][1]);
        r1   = __fadd_rn(r1,   part[ww][2]);
      }
      r0 = __fdiv_rn(r0, sume); r1 = __fdiv_rn(r1, sume);
      float4 cw = CW4[t];
      float ct = fmaf(r0, cw.x, fmaf(r1, cw.y, cw.z));
      HtLp[IDX1(t)] = __fadd_rn(DF4p[IDX4(t)].w, ct);
    }
    __syncthreads();

    // S5: decoder logits (same task map)
    float accD = 0.f;
    if (activeS) {
      #pragma unroll 4
      for (int j = 0; j < 64; ++j) {
        float4 df = DF4p[b4 + j];
        float ctd = HtLp[b1 + j];
        float d = fmaf(df.y, s1r, __fmul_rn(df.x, s0r));
        d = __fadd_rn(d, ctd);
        accD = fmaf(df.z, fast_tanhf(d), accD);
      }
    }
    float sc2 = activeS ? __fadd_rn(accD, __shfl_xor(accD, 1)) : 0.f;

    // decoder raw exp/sum + gumbel argmax (merged butterfly)
    float e2 = activeS ? expf(sc2) : 0.f;
    if (activeS && (t & 1) == 0) ex2L[s] = e2;
    {
      uint32_t k0 = keysL[2*step], k1 = keysL[2*step + 1];
      float gv = -INFINITY;
      int gidx = 1 << 20;
      if (activeS) {
        uint32_t q0, q1;
        threefry2x32(k0, k1, 0u, (uint32_t)(b*NS + s), q0, q1);
        gv = __fadd_rn(bits_to_gumbel(q0 ^ q1), sc2);
        gidx = s;
      }
      float sm = e2;
      #pragma unroll
      for (int mm = 2; mm < 64; mm <<= 1) {
        sm = __fadd_rn(sm, __shfl_xor(sm, mm));
        float ov = __shfl_xor(gv, mm); int oi = __shfl_xor(gidx, mm);
        if (ov > gv || (ov == gv && oi < gidx)) { gv = ov; gidx = oi; }
      }
      if ((t & 63) == 0) { part[w][3] = sm; part[w][4] = gv; partI[w] = gidx; }
    }
    __syncthreads();

    if (t == 0) {
      float bv = part[0][4]; int bi = partI[0];
      float sume2 = part[0][3];
      #pragma unroll
      for (int ww = 1; ww < NWAVE; ++ww) {
        float vv = part[ww][4]; int ii = partI[ww];
        if (vv > bv || (vv == bv && ii < bi)) { bv = vv; bi = ii; }
        sume2 = __fadd_rn(sume2, part[ww][3]);
      }
      out[(size_t)b*NS + step] = (float)bi;
      out[(size_t)NB*NS + (size_t)b*NS + step] = __fdiv_rn(ex2L[bi], sume2);
      xpL[0] = st0L[bi]; xpL[1] = st1L[bi];
    }
    __syncthreads();
  }
}

// ---------------- host launch ----------------
extern "C" void kernel_launch(void* const* d_in, const int* in_sizes, int n_in,
                              void* d_out, int out_size, void* d_ws, size_t ws_size,
                              hipStream_t stream) {
  (void)in_sizes; (void)n_in; (void)out_size; (void)d_ws; (void)ws_size;
  const float* stat = (const float*)d_in[0];
  const float* dyn  = (const float*)d_in[1];
  const float* sW   = (const float*)d_in[2];
  const float* sb   = (const float*)d_in[3];
  const float* dW   = (const float*)d_in[4];
  const float* db   = (const float*)d_in[5];
  const float* x0   = (const float*)d_in[6];
  const float* h0   = (const float*)d_in[7];
  const float* Wemb = (const float*)d_in[8];
  const float* bemb = (const float*)d_in[9];
  const float* Wih  = (const float*)d_in[10];
  const float* Whh  = (const float*)d_in[11];
  const float* bih  = (const float*)d_in[12];
  const float* bhh  = (const float*)d_in[13];
  const float* Wa   = (const float*)d_in[14];
  const float* va   = (const float*)d_in[15];
  const float* Wd   = (const float*)d_in[16];
  const float* vd   = (const float*)d_in[17];
  float* out = (float*)d_out;

  k_decode<<<NB, 512, 0, stream>>>(stat, dyn, sW, sb, dW, db, x0, h0,
                                   Wemb, bemb, Wih, Whh, bih, bhh,
                                   Wa, va, Wd, vd, out);
}

// Round 10
// 6057.088 us; speedup vs baseline: 1.6550x; 1.1086x over previous
//
#include <hip/hip_runtime.h>
#include <stdint.h>
#include <math.h>

#define NB 512
#define NS 200
#define NH 128
#define NH3 384
#define NWAVE 8

// padded LDS index maps (break half-offset bank aliasing) — validated r9
#define IDX4(h) ((h) + (((h) >> 6) << 2))    // float4 arrays: +4 per 64
#define IDX1(h) ((h) + (((h) >> 6) << 4))    // float  arrays: +16 per 64

// ---------------- XLA-exact scalar helpers (GRU gate path only) ----------------
__device__ __forceinline__ float xla_tanhf(float x) {
  float cx = fminf(fmaxf(x, -9.0f), 9.0f);
  float x2 = __fmul_rn(cx, cx);
  float p = -2.76076847742355e-16f;
  p = __fadd_rn(__fmul_rn(x2, p), 2.00018790482477e-13f);
  p = __fadd_rn(__fmul_rn(x2, p), -8.60467152213735e-11f);
  p = __fadd_rn(__fmul_rn(x2, p), 5.12229709037114e-08f);
  p = __fadd_rn(__fmul_rn(x2, p), 1.48572235717979e-05f);
  p = __fadd_rn(__fmul_rn(x2, p), 6.37261928875436e-04f);
  p = __fadd_rn(__fmul_rn(x2, p), 4.89352455891786e-03f);
  p = __fmul_rn(cx, p);
  float q = 1.19825839466702e-06f;
  q = __fadd_rn(__fmul_rn(x2, q), 1.18534705686654e-04f);
  q = __fadd_rn(__fmul_rn(x2, q), 2.26843463243900e-03f);
  q = __fadd_rn(__fmul_rn(x2, q), 4.89352518554385e-03f);
  float r = __fdiv_rn(p, q);
  return (fabsf(x) < 0.0004f) ? x : r;
}

__device__ __forceinline__ float xla_sigmoidf(float x) {
  return __fadd_rn(0.5f, __fmul_rn(0.5f, xla_tanhf(__fmul_rn(0.5f, x))));
}

// exp-based fast tanh for logit paths (S4/S5): tanh(x) = 1 - 2/(e^{2x}+1)
// ~4 VALU ops via v_exp_f32 + v_rcp_f32; graceful at +-inf;
// |diff vs xla_tanhf| <= ~4 ulp -> per-logit error ~6e-7 (validated class)
__device__ __forceinline__ float fast_tanhf(float x) {
  float e = __expf(__fmul_rn(x, 2.0f));
  float r = __builtin_amdgcn_rcpf(__fadd_rn(e, 1.0f));
  return fmaf(-2.0f, r, 1.0f);
}

__device__ __forceinline__ uint32_t rotl32(uint32_t v, int r) {
  return (v << r) | (v >> (32 - r));
}
__device__ __forceinline__ void threefry2x32(uint32_t k0, uint32_t k1,
                                             uint32_t x0, uint32_t x1,
                                             uint32_t& o0, uint32_t& o1) {
  uint32_t k2 = k0 ^ k1 ^ 0x1BD11BDAu;
  x0 += k0; x1 += k1;
  #define TFR(r) { x0 += x1; x1 = rotl32(x1, r); x1 ^= x0; }
  TFR(13) TFR(15) TFR(26) TFR(6)
  x0 += k1; x1 += k2 + 1u;
  TFR(17) TFR(29) TFR(16) TFR(24)
  x0 += k2; x1 += k0 + 2u;
  TFR(13) TFR(15) TFR(26) TFR(6)
  x0 += k0; x1 += k1 + 3u;
  TFR(17) TFR(29) TFR(16) TFR(24)
  x0 += k1; x1 += k2 + 4u;
  TFR(13) TFR(15) TFR(26) TFR(6)
  x0 += k2; x1 += k0 + 5u;
  #undef TFR
  o0 = x0; o1 = x1;
}

__device__ __forceinline__ float bits_to_gumbel(uint32_t bits) {
  const float kTiny = 1.1754943508222875e-38f;
  float f = __fsub_rn(__uint_as_float((bits >> 9) | 0x3F800000u), 1.0f);
  float u = __fadd_rn(__fmul_rn(f, __fsub_rn(1.0f, kTiny)), kTiny);
  u = fmaxf(kTiny, u);
  return -logf(-logf(u));
}

// ---------------- persistent kernel: 1 row/block, 512 threads ----------------
// S4/S5 task map: t<400 -> s = t>>1, half = t&1 -> h in [half*64, +64)
__global__ __launch_bounds__(512, 4) void k_decode(
    const float* __restrict__ stat, const float* __restrict__ dyn,
    const float* __restrict__ sW,   const float* __restrict__ sb,
    const float* __restrict__ dW,   const float* __restrict__ db,
    const float* __restrict__ x0,   const float* __restrict__ h0,
    const float* __restrict__ Wemb, const float* __restrict__ bemb,
    const float* __restrict__ Wih,  const float* __restrict__ Whh,
    const float* __restrict__ bih,  const float* __restrict__ bhh,
    const float* __restrict__ Wa,   const float* __restrict__ va,
    const float* __restrict__ Wd,   const float* __restrict__ vd,
    float* __restrict__ out) {

  __shared__ __align__(16) float st0L[NS], st1L[NS], dy0L[NS], dy1L[NS];
  __shared__ float4 AF4p[132];             // {As0,As1,Ad0,Ad1} padded
  __shared__ float4 DF4p[132];             // {Ds0,Ds1,vd,Dc}   padded
  __shared__ float4 CW4[NH];               // {Cw0,Cw1,Cwb,0}
  __shared__ float  vaP[144];              // va padded
  __shared__ float  AcL[NH];               // attention const (folded in S3)
  __shared__ float WembL[2*NH], bembL[NH];
  __shared__ float bihL[NH3], bhhL[NH3];
  __shared__ __align__(16) float embL[NH], hL[NH];
  __shared__ float giL[NH3], ghL[NH3];
  __shared__ float HtLp[144];              // Hterm+Ac, then Cterm+Dc (padded)
  __shared__ float ex2L[NS];
  __shared__ uint32_t keysL[2*NS];
  __shared__ float xpL[2];
  __shared__ float part[NWAVE][8];
  __shared__ int   partI[NWAVE];

  const int t = threadIdx.x;
  const int b = blockIdx.x;
  const int w = t >> 6;                    // wave 0..7
  const int s = t >> 1;                    // candidate node (lane pairs)
  const int h0i = (t & 1) * 64;            // h-half base
  const int b4 = h0i + ((h0i >> 6) << 2);  // padded float4 base (0 or 68)
  const int b1 = h0i + ((h0i >> 6) << 4);  // padded float base  (0 or 80)
  const bool activeS = (t < 2*NS);

  // ---- one-time setup ----
  if (t < NS) {
    st0L[t] = stat[(size_t)b*2*NS + t];
    st1L[t] = stat[(size_t)b*2*NS + NS + t];
    dy0L[t] = dyn[(size_t)b*2*NS + t];
    dy1L[t] = dyn[(size_t)b*2*NS + NS + t];
    uint32_t q0, q1;
    threefry2x32(0u, 42u, 0u, (uint32_t)t, q0, q1);
    keysL[2*t] = q0; keysL[2*t + 1] = q1;
  }
  if (t < NH) {
    int h = t;
    const float* war = Wa + (size_t)h * NH3;
    float as0 = 0.f, as1 = 0.f, ad0 = 0.f, ad1 = 0.f, ac = 0.f;
    for (int k = 0; k < NH; ++k) {
      as0 = fmaf(war[k],     sW[k*2+0], as0);
      as1 = fmaf(war[k],     sW[k*2+1], as1);
      ad0 = fmaf(war[NH+k],  dW[k*2+0], ad0);
      ad1 = fmaf(war[NH+k],  dW[k*2+1], ad1);
      ac  = fmaf(war[k],     sb[k],     ac);
    }
    for (int k = 0; k < NH; ++k) ac = fmaf(war[NH+k], db[k], ac);
    AF4p[IDX4(h)] = make_float4(as0, as1, ad0, ad1);
    vaP[IDX1(h)] = va[h];
    AcL[h] = ac;

    const float* wdr = Wd + (size_t)h * 256;
    float ds0 = 0.f, ds1 = 0.f, dc = 0.f, c0 = 0.f, c1 = 0.f, cb = 0.f;
    for (int k = 0; k < NH; ++k) {
      ds0 = fmaf(wdr[k],    sW[k*2+0], ds0);
      ds1 = fmaf(wdr[k],    sW[k*2+1], ds1);
      dc  = fmaf(wdr[k],    sb[k],     dc);
      c0  = fmaf(wdr[NH+k], sW[k*2+0], c0);
      c1  = fmaf(wdr[NH+k], sW[k*2+1], c1);
      cb  = fmaf(wdr[NH+k], sb[k],     cb);
    }
    DF4p[IDX4(h)] = make_float4(ds0, ds1, vd[h], dc);
    CW4[h] = make_float4(c0, c1, cb, 0.f);

    bembL[h] = bemb[h];
    WembL[2*h]   = Wemb[2*h];
    WembL[2*h+1] = Wemb[2*h+1];
    hL[h] = h0[h];
  }
  for (int i = t; i < NH3; i += 512) { bihL[i] = bih[i]; bhhL[i] = bhh[i]; }
  if (t == 0) { xpL[0] = x0[0]; xpL[1] = x0[1]; }
  __syncthreads();

  // per-s inputs hoisted (pair-uniform)
  float s0r = 0.f, s1r = 0.f, d0r = 0.f, d1r = 0.f;
  if (activeS) { s0r = st0L[s]; s1r = st1L[s]; d0r = dy0L[s]; d1r = dy1L[s]; }

  // ---- 200 decode steps ----
  for (int step = 0; step < NS; ++step) {
    // S0: emb = x @ Wemb^T + bemb (t<128)
    if (t < NH) {
      float e = fmaf(xpL[1], WembL[t*2+1], __fmul_rn(xpL[0], WembL[t*2+0]));
      embL[t] = __fadd_rn(e, bembL[t]);
    }
    __syncthreads();

    // S1: 768 GRU dots over 512 threads (per-dot chain bit-identical to r5-r9)
    if (t < 256) {
      const float4* wp0 = (const float4*)(Wih + (size_t)t * NH);
      const float4* wp1 = (const float4*)(Whh + (size_t)(NH + t) * NH);
      const float4* e4 = (const float4*)embL;
      const float4* h4 = (const float4*)hL;
      float a0 = 0.f, a1 = 0.f;
      #pragma unroll 8
      for (int k4 = 0; k4 < 32; ++k4) {
        float4 c0 = wp0[k4], c1 = wp1[k4];
        float4 ev = e4[k4],  hv = h4[k4];
        a0 = fmaf(c0.x, ev.x, a0); a0 = fmaf(c0.y, ev.y, a0);
        a0 = fmaf(c0.z, ev.z, a0); a0 = fmaf(c0.w, ev.w, a0);
        a1 = fmaf(c1.x, hv.x, a1); a1 = fmaf(c1.y, hv.y, a1);
        a1 = fmaf(c1.z, hv.z, a1); a1 = fmaf(c1.w, hv.w, a1);
      }
      giL[t]      = __fadd_rn(a0, bihL[t]);
      ghL[NH + t] = __fadd_rn(a1, bhhL[NH + t]);
    } else {
      const bool isWih = (t < NH3);
      const float4* wp = isWih
          ? (const float4*)(Wih + (size_t)t * NH)
          : (const float4*)(Whh + (size_t)(t - NH3) * NH);
      const float4* op = isWih ? (const float4*)embL : (const float4*)hL;
      float a0 = 0.f;
      #pragma unroll 8
      for (int k4 = 0; k4 < 32; ++k4) {
        float4 c = wp[k4], v = op[k4];
        a0 = fmaf(c.x, v.x, a0); a0 = fmaf(c.y, v.y, a0);
        a0 = fmaf(c.z, v.z, a0); a0 = fmaf(c.w, v.w, a0);
      }
      if (isWih) giL[t]       = __fadd_rn(a0, bihL[t]);
      else       ghL[t - NH3] = __fadd_rn(a0, bhhL[t - NH3]);
    }
    __syncthreads();

    // S2: gates (torch r,z,n) EXACT XLA math, h_new in place (t<128)
    if (t < NH) {
      float r = xla_sigmoidf(__fadd_rn(giL[t],      ghL[t]));
      float z = xla_sigmoidf(__fadd_rn(giL[t+NH],   ghL[t+NH]));
      float n = xla_tanhf(__fadd_rn(giL[t+2*NH], __fmul_rn(r, ghL[t+2*NH])));
      float hv = hL[t];
      hL[t] = __fadd_rn(__fmul_rn(__fsub_rn(1.0f, z), n), __fmul_rn(z, hv));
    }
    __syncthreads();

    // S3: Hterm = Wa[:,256:384] @ h_new, +Ac folded (t<128)
    if (t < NH) {
      const float4* war = (const float4*)(Wa + (size_t)t*NH3 + 2*NH);
      const float4* hn4 = (const float4*)hL;
      float acc = 0.f;
      #pragma unroll 8
      for (int k4 = 0; k4 < 32; ++k4) {
        float4 a = war[k4], hv = hn4[k4];
        acc = fmaf(a.x, hv.x, acc); acc = fmaf(a.y, hv.y, acc);
        acc = fmaf(a.z, hv.z, acc); acc = fmaf(a.w, hv.w, acc);
      }
      HtLp[IDX1(t)] = __fadd_rn(acc, AcL[t]);
    }
    __syncthreads();

    // S4: attention scores; half-partials, padded LDS, exp-based tanh
    float acc = 0.f;
    if (activeS) {
      #pragma unroll 4
      for (int j = 0; j < 64; ++j) {
        float4 af = AF4p[b4 + j];
        float vah = vaP[b1 + j];
        float ath = HtLp[b1 + j];
        float e = fmaf(af.y, s1r, __fmul_rn(af.x, s0r));
        e = fmaf(af.z, d0r, e);
        e = fmaf(af.w, d1r, e);
        e = __fadd_rn(e, ath);
        acc = fmaf(vah, fast_tanhf(e), acc);
      }
    }
    float sc = activeS ? __fadd_rn(acc, __shfl_xor(acc, 1)) : 0.f;

    // raw exp (no max-sub; bounded logits) + sums butterfly
    float exv = activeS ? __expf(sc) : 0.f;
    {
      float sm = exv;
      float c0 = __fmul_rn(exv, s0r);
      float c1 = __fmul_rn(exv, s1r);
      #pragma unroll
      for (int mm = 2; mm < 64; mm <<= 1) {
        sm = __fadd_rn(sm, __shfl_xor(sm, mm));
        c0 = __fadd_rn(c0, __shfl_xor(c0, mm));
        c1 = __fadd_rn(c1, __shfl_xor(c1, mm));
      }
      if ((t & 63) == 0) { part[w][0] = sm; part[w][1] = c0; part[w][2] = c1; }
    }
    __syncthreads();

    // Cterm (overwrite HtLp), +Dc folded, t<128
    if (t < NH) {
      float sume = part[0][0], r0 = part[0][1], r1 = part[0][2];
      #pragma unroll
      for (int ww = 1; ww < NWAVE; ++ww) {
        sume = __fadd_rn(sume, part[ww][0]);
        r0   = __fadd_rn(r0,   part[ww][1]);
        r1   = __fadd_rn(r1,   part[ww][2]);
      }
      r0 = __fdiv_rn(r0, sume); r1 = __fdiv_rn(r1, sume);
      float4 cw = CW4[t];
      float ct = fmaf(r0, cw.x, fmaf(r1, cw.y, cw.z));
      HtLp[IDX1(t)] = __fadd_rn(DF4p[IDX4(t)].w, ct);
    }
    __syncthreads();

    // S5: decoder logits (same task map, exp-based tanh)
    float accD = 0.f;
    if (activeS) {
      #pragma unroll 4
      for (int j = 0; j < 64; ++j) {
        float4 df = DF4p[b4 + j];
        float ctd = HtLp[b1 + j];
        float d = fmaf(df.y, s1r, __fmul_rn(df.x, s0r));
        d = __fadd_rn(d, ctd);
        accD = fmaf(df.z, fast_tanhf(d), accD);
      }
    }
    float sc2 = activeS ? __fadd_rn(accD, __shfl_xor(accD, 1)) : 0.f;

    // decoder raw exp/sum + gumbel argmax (merged butterfly)
    float e2 = activeS ? __expf(sc2) : 0.f;
    if (activeS && (t & 1) == 0) ex2L[s] = e2;
    {
      uint32_t k0 = keysL[2*step], k1 = keysL[2*step + 1];
      float gv = -INFINITY;
      int gidx = 1 << 20;
      if (activeS) {
        uint32_t q0, q1;
        threefry2x32(k0, k1, 0u, (uint32_t)(b*NS + s), q0, q1);
        gv = __fadd_rn(bits_to_gumbel(q0 ^ q1), sc2);
        gidx = s;
      }
      float sm = e2;
      #pragma unroll
      for (int mm = 2; mm < 64; mm <<= 1) {
        sm = __fadd_rn(sm, __shfl_xor(sm, mm));
        float ov = __shfl_xor(gv, mm); int oi = __shfl_xor(gidx, mm);
        if (ov > gv || (ov == gv && oi < gidx)) { gv = ov; gidx = oi; }
      }
      if ((t & 63) == 0) { part[w][3] = sm; part[w][4] = gv; partI[w] = gidx; }
    }
    __syncthreads();

    if (t == 0) {
      float bv = part[0][4]; int bi = partI[0];
      float sume2 = part[0][3];
      #pragma unroll
      for (int ww = 1; ww < NWAVE; ++ww) {
        float vv = part[ww][4]; int ii = partI[ww];
        if (vv > bv || (vv == bv && ii < bi)) { bv = vv; bi = ii; }
        sume2 = __fadd_rn(sume2, part[ww][3]);
      }
      out[(size_t)b*NS + step] = (float)bi;
      out[(size_t)NB*NS + (size_t)b*NS + step] = __fdiv_rn(ex2L[bi], sume2);
      xpL[0] = st0L[bi]; xpL[1] = st1L[bi];
    }
    __syncthreads();
  }
}

// ---------------- host launch ----------------
extern "C" void kernel_launch(void* const* d_in, const int* in_sizes, int n_in,
                              void* d_out, int out_size, void* d_ws, size_t ws_size,
                              hipStream_t stream) {
  (void)in_sizes; (void)n_in; (void)out_size; (void)d_ws; (void)ws_size;
  const float* stat = (const float*)d_in[0];
  const float* dyn  = (const float*)d_in[1];
  const float* sW   = (const float*)d_in[2];
  const float* sb   = (const float*)d_in[3];
  const float* dW   = (const float*)d_in[4];
  const float* db   = (const float*)d_in[5];
  const float* x0   = (const float*)d_in[6];
  const float* h0   = (const float*)d_in[7];
  const float* Wemb = (const float*)d_in[8];
  const float* bemb = (const float*)d_in[9];
  const float* Wih  = (const float*)d_in[10];
  const float* Whh  = (const float*)d_in[11];
  const float* bih  = (const float*)d_in[12];
  const float* bhh  = (const float*)d_in[13];
  const float* Wa   = (const float*)d_in[14];
  const float* va   = (const float*)d_in[15];
  const float* Wd   = (const float*)d_in[16];
  const float* vd   = (const float*)d_in[17];
  float* out = (float*)d_out;

  k_decode<<<NB, 512, 0, stream>>>(stat, dyn, sW, sb, dW, db, x0, h0,
                                   Wemb, bemb, Wih, Whh, bih, bhh,
                                   Wa, va, Wd, vd, out);
}